// Round 2
// baseline (701.339 us; speedup 1.0000x reference)
//
#include <hip/hip_runtime.h>

// MMoE: B=16384, D=1024, E=8, H=512, T=256, TASKS=3
// Batch-chunked pipeline (chunk size Bc chosen at launch from ws_size):
//   prologue: cvt x->bf16, transpose We1/We2/Wt1 to [N][K] bf16, fp32 gates
//   per chunk: gemm1 -> h1c, gemm2 -> eoc, combine -> tic, gemm(tower1) -> thc,
//              tower2 dot+sigmoid -> d_out
//
// Workspace: fixed 48,496,640 B (xb 33.5M, W1T 8.4M, W2T 4.2M, Wt1T 0.8M,
// gates 1.6M) + Bc*20992 B of chunk buffers. Bc in {512..8192} adapts to
// ws_size (R1 crashed with an unconditional 317 MB layout — suspected
// workspace overrun).

#define BM 128
#define BN 128
#define BK 64

typedef __attribute__((ext_vector_type(8))) short short8;
typedef __attribute__((ext_vector_type(4))) float floatx4;
typedef __attribute__((ext_vector_type(4))) unsigned short ushortx4;
typedef __attribute__((ext_vector_type(8))) unsigned short ushortx8;

__device__ __forceinline__ unsigned short f32_to_bf16(float f) {
  unsigned int u = __float_as_uint(f);
  u += 0x7fffu + ((u >> 16) & 1u);   // round-to-nearest-even (no NaNs in this net)
  return (unsigned short)(u >> 16);
}
__device__ __forceinline__ float bf16_to_f32(unsigned short h) {
  return __uint_as_float(((unsigned int)h) << 16);
}

__device__ __forceinline__ void async_cp16(const void* g, void* lds) {
  __builtin_amdgcn_global_load_lds(
      (const __attribute__((address_space(1))) void*)g,
      (__attribute__((address_space(3))) void*)lds, 16, 0, 0);
}

// ---------------- fp32 -> bf16 convert (x) ----------------
__global__ void cvt_x_kernel(const float* __restrict__ x, unsigned short* __restrict__ xb) {
  size_t i = ((size_t)blockIdx.x * blockDim.x + threadIdx.x) * 4;
  floatx4 v = *(const floatx4*)(x + i);
  ushortx4 o;
#pragma unroll
  for (int j = 0; j < 4; j++) o[j] = f32_to_bf16(v[j]);
  *(ushortx4*)(xb + i) = o;
}

// ---------------- [z][K][N] fp32 -> [z][N][K] bf16 ----------------
__global__ void transpose_cvt_kernel(const float* __restrict__ in,
                                     unsigned short* __restrict__ out,
                                     int K, int N) {
  __shared__ float tile[32][33];
  const size_t zoff = (size_t)blockIdx.z * K * N;
  int n0 = blockIdx.x * 32, k0 = blockIdx.y * 32;
  for (int i = threadIdx.y; i < 32; i += 8)
    tile[i][threadIdx.x] = in[zoff + (size_t)(k0 + i) * N + n0 + threadIdx.x];
  __syncthreads();
  for (int i = threadIdx.y; i < 32; i += 8)
    out[zoff + (size_t)(n0 + i) * K + k0 + threadIdx.x] = f32_to_bf16(tile[threadIdx.x][i]);
}

// ---------------- gates: fp32 logits + softmax over E=8 ----------------
__global__ __launch_bounds__(256) void gates_kernel(
    const float* __restrict__ x, const float* __restrict__ Wg,
    const float* __restrict__ bg, float* __restrict__ gout) {
  __shared__ float lsum[4][24];
  int wave = threadIdx.x >> 6, lane = threadIdx.x & 63;
  int b = blockIdx.x * 4 + wave;
  const float* xr = x + (size_t)b * 1024;
  float xv[16];
#pragma unroll
  for (int j = 0; j < 16; j++) xv[j] = xr[lane + 64 * j];
  float acc[24];
#pragma unroll
  for (int te = 0; te < 24; te++) {
    int t = te >> 3, e = te & 7;
    const float* w = Wg + (size_t)t * 8192 + e;   // Wg[t][k][e], stride 8 over k
    float a = 0.f;
#pragma unroll
    for (int j = 0; j < 16; j++) a += xv[j] * w[(lane + 64 * j) * 8];
    acc[te] = a;
  }
#pragma unroll
  for (int te = 0; te < 24; te++) {
    float a = acc[te];
#pragma unroll
    for (int off = 32; off > 0; off >>= 1) a += __shfl_xor(a, off, 64);
    if (lane == 0) lsum[wave][te] = a;
  }
  __syncthreads();
  int tid = threadIdx.x;
  if (tid < 96) {   // groups of 8 are 8-lane-aligned (24 = 3*8), never straddle a wave
    int w = tid / 24, te = tid % 24, t = te >> 3, e = te & 7;
    int b2 = blockIdx.x * 4 + w;
    float logit = lsum[w][te] + bg[t * 8 + e];
    float m = logit;
    m = fmaxf(m, __shfl_xor(m, 4, 64));
    m = fmaxf(m, __shfl_xor(m, 2, 64));
    m = fmaxf(m, __shfl_xor(m, 1, 64));
    float ex = __expf(logit - m);
    float s = ex;
    s += __shfl_xor(s, 4, 64);
    s += __shfl_xor(s, 2, 64);
    s += __shfl_xor(s, 1, 64);
    gout[((size_t)t * 16384 + b2) * 8 + e] = ex / s;
  }
}

// ---------------- m97-style bf16 GEMM: C = relu(A * B^T + bias), bf16 out ----------------
// A: [M][K] bf16 row stride lda, per-z offset aOffZ (elements)
// Bt: [N][K] bf16 contiguous per z (bOffZ elements per z)
// C: bf16, element (m,n) at Cbase + z*cOffZ + m*ldc + n
__global__ __launch_bounds__(256) void gemm_bt_relu(
    const unsigned short* __restrict__ Abase, long aOffZ, int lda,
    const unsigned short* __restrict__ Bbase, long bOffZ,
    const float* __restrict__ biasBase, int biasOffZ,
    unsigned short* __restrict__ Cbase, long cOffZ, int ldc,
    int K) {
  __shared__ __align__(16) unsigned short As[BM * BK];
  __shared__ __align__(16) unsigned short Bs[BN * BK];
  const int tid = threadIdx.x;
  const int z = blockIdx.z;
  const unsigned short* A = Abase + (size_t)aOffZ * z + (size_t)blockIdx.x * BM * lda;
  const unsigned short* Bt = Bbase + (size_t)bOffZ * z + (size_t)blockIdx.y * BN * K;
  const float* bias = biasBase + (size_t)biasOffZ * z + blockIdx.y * BN;
  unsigned short* C = Cbase + (size_t)cOffZ * z + (size_t)blockIdx.x * BM * ldc + blockIdx.y * BN;

  const int wave = tid >> 6, lane = tid & 63;
  const int wm = (wave >> 1) * 64, wn = (wave & 1) * 64;
  const int lm = lane & 15, lq = lane >> 4;

  floatx4 acc[4][4] = {};

  const int sr = tid >> 3;          // staging row 0..31
  const int sc = (tid & 7) * 8;     // staging col chunk (elements)

  for (int kt = 0; kt < K; kt += BK) {
#pragma unroll
    for (int i = 0; i < 4; i++)
      async_cp16(A + (size_t)(sr + 32 * i) * lda + kt + sc,
                 (char*)As + i * 4096 + tid * 16);
#pragma unroll
    for (int i = 0; i < 4; i++)
      async_cp16(Bt + (size_t)(sr + 32 * i) * K + kt + sc,
                 (char*)Bs + i * 4096 + tid * 16);
    __syncthreads();   // drains vmcnt -> staged tiles visible
#pragma unroll
    for (int ks = 0; ks < 2; ks++) {
      short8 af[4], bf[4];
#pragma unroll
      for (int i = 0; i < 4; i++)
        af[i] = *(const short8*)(As + (wm + 16 * i + lm) * BK + ks * 32 + lq * 8);
#pragma unroll
      for (int j = 0; j < 4; j++)
        bf[j] = *(const short8*)(Bs + (wn + 16 * j + lm) * BK + ks * 32 + lq * 8);
#pragma unroll
      for (int i = 0; i < 4; i++)
#pragma unroll
        for (int j = 0; j < 4; j++)
          acc[i][j] = __builtin_amdgcn_mfma_f32_16x16x32_bf16(af[i], bf[j], acc[i][j], 0, 0, 0);
    }
    __syncthreads();   // protect LDS reuse next iter
  }

#pragma unroll
  for (int i = 0; i < 4; i++) {
    const int row = wm + 16 * i + lq * 4;
#pragma unroll
    for (int j = 0; j < 4; j++) {
      const int col = wn + 16 * j + lm;
      const float bv = bias[col];
#pragma unroll
      for (int v = 0; v < 4; v++) {
        float val = fmaxf(acc[i][j][v] + bv, 0.0f);
        C[(size_t)(row + v) * ldc + col] = f32_to_bf16(val);
      }
    }
  }
}

// ---------------- combine: tic[t,bl,h] = sum_e gates[t,b0+bl,e] * eoc[bl,e,h] ----------------
__global__ void combine_kernel(const unsigned short* __restrict__ eo,
                               const float* __restrict__ gates,
                               unsigned short* __restrict__ ti,
                               int b0, int Bc) {
  int tid = blockIdx.x * 256 + threadIdx.x;
  int bl = tid >> 6;                 // chunk-local row
  int hc = (tid & 63) << 3;
  float g[3][8];
#pragma unroll
  for (int t = 0; t < 3; t++) {
    const floatx4* gp = (const floatx4*)(gates + ((size_t)t * 16384 + b0 + bl) * 8);
    floatx4 g0 = gp[0], g1 = gp[1];
#pragma unroll
    for (int j = 0; j < 4; j++) { g[t][j] = g0[j]; g[t][4 + j] = g1[j]; }
  }
  float out[3][8] = {};
#pragma unroll
  for (int e = 0; e < 8; e++) {
    ushortx8 v = *(const ushortx8*)(eo + ((size_t)bl * 8 + e) * 512 + hc);
#pragma unroll
    for (int j = 0; j < 8; j++) {
      float f = bf16_to_f32(v[j]);
#pragma unroll
      for (int t = 0; t < 3; t++) out[t][j] += g[t][e] * f;
    }
  }
#pragma unroll
  for (int t = 0; t < 3; t++) {
    ushortx8 o;
#pragma unroll
    for (int j = 0; j < 8; j++) o[j] = f32_to_bf16(out[t][j]);
    *(ushortx8*)(ti + ((size_t)t * Bc + bl) * 512 + hc) = o;
  }
}

// ---------------- tower2: out[t*16384+b0+bl] = sigmoid(thc[t,bl,:] . Wt2[t] + bt2[t]) ----------------
__global__ void tower2_kernel(const unsigned short* __restrict__ th,
                              const float* __restrict__ Wt2,
                              const float* __restrict__ bt2,
                              float* __restrict__ out,
                              int b0, int bcShift) {
  int wave = threadIdx.x >> 6, lane = threadIdx.x & 63;
  int row = blockIdx.x * 4 + wave;       // 0 .. 3*Bc-1 ; row = t*Bc + bl
  int t = row >> bcShift;
  int bl = row & ((1 << bcShift) - 1);
  const unsigned short* r = th + (size_t)row * 256;
  int k = lane * 4;
  ushortx4 v = *(const ushortx4*)(r + k);
  float a = 0.f;
#pragma unroll
  for (int j = 0; j < 4; j++) a += bf16_to_f32(v[j]) * Wt2[t * 256 + k + j];
#pragma unroll
  for (int off = 32; off > 0; off >>= 1) a += __shfl_xor(a, off, 64);
  if (lane == 0) out[(t << 14) + b0 + bl] = 1.f / (1.f + __expf(-(a + bt2[t])));
}

extern "C" void kernel_launch(void* const* d_in, const int* in_sizes, int n_in,
                              void* d_out, int out_size, void* d_ws, size_t ws_size,
                              hipStream_t stream) {
  (void)in_sizes; (void)n_in; (void)out_size;
  const float* x   = (const float*)d_in[0];
  const float* We1 = (const float*)d_in[1];
  const float* be1 = (const float*)d_in[2];
  const float* We2 = (const float*)d_in[3];
  const float* be2 = (const float*)d_in[4];
  const float* Wg  = (const float*)d_in[5];
  const float* bg  = (const float*)d_in[6];
  const float* Wt1 = (const float*)d_in[7];
  const float* bt1 = (const float*)d_in[8];
  const float* Wt2 = (const float*)d_in[9];
  const float* bt2 = (const float*)d_in[10];
  float* out = (float*)d_out;

  char* ws = (char*)d_ws;
  unsigned short* xb   = (unsigned short*)(ws + 0);            // 33,554,432
  unsigned short* W1T  = (unsigned short*)(ws + 33554432);     //  8,388,608
  unsigned short* W2T  = (unsigned short*)(ws + 41943040);     //  4,194,304
  unsigned short* Wt1T = (unsigned short*)(ws + 46137344);     //    786,432
  float*          gts  = (float*)(ws + 46923776);              //  1,572,864
  const size_t fixed = 48496640;

  // Adaptive chunk size: per-chunk buffers need Bc*20992 bytes.
  size_t rem = ws_size > fixed ? ws_size - fixed : 0;
  int Bc = 8192;
  while (Bc > 512 && (size_t)Bc * 20992 > rem) Bc >>= 1;
  const int nc = 16384 / Bc;
  int bcShift = 0;
  while ((1 << bcShift) < Bc) bcShift++;

  char* cb = ws + fixed;
  unsigned short* h1c = (unsigned short*)(cb);                                    // Bc*8192 B
  unsigned short* eoc = (unsigned short*)(cb + (size_t)Bc * 8192);                // Bc*8192 B
  unsigned short* tic = (unsigned short*)(cb + (size_t)Bc * 16384);               // Bc*3072 B
  unsigned short* thc = (unsigned short*)(cb + (size_t)Bc * 16384 + (size_t)Bc * 3072); // Bc*1536 B

  // --- prologue (chunk-independent) ---
  cvt_x_kernel<<<16384, 256, 0, stream>>>(x, xb);
  transpose_cvt_kernel<<<dim3(16, 32, 8), dim3(32, 8), 0, stream>>>(We1, W1T, 1024, 512);
  transpose_cvt_kernel<<<dim3(16, 16, 8), dim3(32, 8), 0, stream>>>(We2, W2T, 512, 512);
  transpose_cvt_kernel<<<dim3(8, 16, 3),  dim3(32, 8), 0, stream>>>(Wt1, Wt1T, 512, 256);
  gates_kernel<<<4096, 256, 0, stream>>>(x, Wg, bg, gts);

  // --- per-chunk pipeline ---
  for (int c = 0; c < nc; c++) {
    const unsigned short* xbc = xb + (size_t)c * Bc * 1024;
    // h1c = relu(x_chunk @ We1 + be1)     M=Bc N=512 K=1024 per expert
    gemm_bt_relu<<<dim3(Bc / 128, 4, 8), 256, 0, stream>>>(
        xbc, 0L, 1024, W1T, 524288L, be1, 512, h1c, 512L, 4096, 1024);
    // eoc = relu(h1c @ We2 + be2)         M=Bc N=512 K=512 per expert
    gemm_bt_relu<<<dim3(Bc / 128, 4, 8), 256, 0, stream>>>(
        h1c, 512L, 4096, W2T, 262144L, be2, 512, eoc, 512L, 4096, 512);
    // tic[t,bl,:] = sum_e g * eoc
    combine_kernel<<<Bc / 4, 256, 0, stream>>>(eoc, gts, tic, c * Bc, Bc);
    // thc = relu(tic @ Wt1 + bt1)         M=Bc N=256 K=512 per task
    gemm_bt_relu<<<dim3(Bc / 128, 2, 3), 256, 0, stream>>>(
        tic, (long)Bc * 512, 512, Wt1T, 131072L, bt1, 256, thc, (long)Bc * 256, 256, 512);
    // out
    tower2_kernel<<<3 * Bc / 4, 256, 0, stream>>>(thc, Wt2, bt2, out, c * Bc, bcShift);
  }
}

// Round 3
// 593.523 us; speedup vs baseline: 1.1817x; 1.1817x over previous
//
#include <hip/hip_runtime.h>

// MMoE: B=16384, D=1024, E=8, H=512, T=256, TASKS=3
// Batch-chunked pipeline (chunk size Bc chosen at launch from ws_size):
//   prologue: cvt x->bf16, transpose We1/We2/Wt1 to [N][K] bf16,
//             transpose Wg->WgT fp32 [t][e][d], fp32 gates (coalesced)
//   per chunk: gemm1 -> h1c, gemm2 -> eoc, combine -> tic, gemm(tower1) -> thc,
//              tower2 dot+sigmoid -> d_out
//
// R2: 701 us, gates_kernel was 167 us due to stride-8 Wg reads (32 cache
// lines/instr) + VGPR=204 occupancy cap. R3: coalesced WgT + register-only
// softmax epilogue.
//
// Workspace: fixed 48,594,944 B + Bc*20992 B chunk buffers (Bc adapts).

#define BM 128
#define BN 128
#define BK 64

typedef __attribute__((ext_vector_type(8))) short short8;
typedef __attribute__((ext_vector_type(4))) float floatx4;
typedef __attribute__((ext_vector_type(4))) unsigned short ushortx4;
typedef __attribute__((ext_vector_type(8))) unsigned short ushortx8;

__device__ __forceinline__ unsigned short f32_to_bf16(float f) {
  unsigned int u = __float_as_uint(f);
  u += 0x7fffu + ((u >> 16) & 1u);   // round-to-nearest-even (no NaNs in this net)
  return (unsigned short)(u >> 16);
}
__device__ __forceinline__ float bf16_to_f32(unsigned short h) {
  return __uint_as_float(((unsigned int)h) << 16);
}

__device__ __forceinline__ void async_cp16(const void* g, void* lds) {
  __builtin_amdgcn_global_load_lds(
      (const __attribute__((address_space(1))) void*)g,
      (__attribute__((address_space(3))) void*)lds, 16, 0, 0);
}

// ---------------- fp32 -> bf16 convert (x) ----------------
__global__ void cvt_x_kernel(const float* __restrict__ x, unsigned short* __restrict__ xb) {
  size_t i = ((size_t)blockIdx.x * blockDim.x + threadIdx.x) * 4;
  floatx4 v = *(const floatx4*)(x + i);
  ushortx4 o;
#pragma unroll
  for (int j = 0; j < 4; j++) o[j] = f32_to_bf16(v[j]);
  *(ushortx4*)(xb + i) = o;
}

// ---------------- [z][K][N] fp32 -> [z][N][K] bf16 ----------------
__global__ void transpose_cvt_kernel(const float* __restrict__ in,
                                     unsigned short* __restrict__ out,
                                     int K, int N) {
  __shared__ float tile[32][33];
  const size_t zoff = (size_t)blockIdx.z * K * N;
  int n0 = blockIdx.x * 32, k0 = blockIdx.y * 32;
  for (int i = threadIdx.y; i < 32; i += 8)
    tile[i][threadIdx.x] = in[zoff + (size_t)(k0 + i) * N + n0 + threadIdx.x];
  __syncthreads();
  for (int i = threadIdx.y; i < 32; i += 8)
    out[zoff + (size_t)(n0 + i) * K + k0 + threadIdx.x] = f32_to_bf16(tile[threadIdx.x][i]);
}

// ---------------- Wg [3][1024][8] fp32 -> WgT [3][8][1024] fp32 ----------------
__global__ void transpose_wg_kernel(const float* __restrict__ in, float* __restrict__ out) {
  int idx = blockIdx.x * 256 + threadIdx.x;   // 24576 total
  int t = idx >> 13, r = idx & 8191;
  int e = r >> 10, d = r & 1023;
  out[idx] = in[t * 8192 + d * 8 + e];
}

// ---------------- gates: coalesced fp32 logits + softmax over E=8 ----------------
// WgT: [3][8][1024] fp32. One wave per batch row.
__global__ __launch_bounds__(256) void gates_kernel(
    const float* __restrict__ x, const float* __restrict__ WgT,
    const float* __restrict__ bg, float* __restrict__ gout) {
  int wave = threadIdx.x >> 6, lane = threadIdx.x & 63;
  int b = blockIdx.x * 4 + wave;
  const float* xr = x + (size_t)b * 1024;
  float xv[16];
#pragma unroll
  for (int j = 0; j < 16; j++) xv[j] = xr[lane + 64 * j];
  float mylogit = 0.f;
#pragma unroll
  for (int te = 0; te < 24; te++) {
    const float* w = WgT + te * 1024;
    float a = 0.f;
#pragma unroll
    for (int j = 0; j < 16; j++) a += xv[j] * w[lane + 64 * j];
#pragma unroll
    for (int off = 32; off > 0; off >>= 1) a += __shfl_xor(a, off, 64);
    if (lane == te) mylogit = a;   // compile-time te -> cndmask, no LDS
  }
  if (lane < 24) {   // groups of 8 (tasks) are 8-lane aligned; xor 4/2/1 stays in-group
    int t = lane >> 3, e = lane & 7;
    float logit = mylogit + bg[lane];
    float m = logit;
    m = fmaxf(m, __shfl_xor(m, 4, 64));
    m = fmaxf(m, __shfl_xor(m, 2, 64));
    m = fmaxf(m, __shfl_xor(m, 1, 64));
    float ex = __expf(logit - m);
    float s = ex;
    s += __shfl_xor(s, 4, 64);
    s += __shfl_xor(s, 2, 64);
    s += __shfl_xor(s, 1, 64);
    gout[(size_t)t * 131072 + (size_t)b * 8 + e] = ex / s;
  }
}

// ---------------- m97-style bf16 GEMM: C = relu(A * B^T + bias), bf16 out ----------------
// A: [M][K] bf16 row stride lda, per-z offset aOffZ (elements)
// Bt: [N][K] bf16 contiguous per z (bOffZ elements per z)
// C: bf16, element (m,n) at Cbase + z*cOffZ + m*ldc + n
__global__ __launch_bounds__(256) void gemm_bt_relu(
    const unsigned short* __restrict__ Abase, long aOffZ, int lda,
    const unsigned short* __restrict__ Bbase, long bOffZ,
    const float* __restrict__ biasBase, int biasOffZ,
    unsigned short* __restrict__ Cbase, long cOffZ, int ldc,
    int K) {
  __shared__ __align__(16) unsigned short As[BM * BK];
  __shared__ __align__(16) unsigned short Bs[BN * BK];
  const int tid = threadIdx.x;
  const int z = blockIdx.z;
  const unsigned short* A = Abase + (size_t)aOffZ * z + (size_t)blockIdx.x * BM * lda;
  const unsigned short* Bt = Bbase + (size_t)bOffZ * z + (size_t)blockIdx.y * BN * K;
  const float* bias = biasBase + (size_t)biasOffZ * z + blockIdx.y * BN;
  unsigned short* C = Cbase + (size_t)cOffZ * z + (size_t)blockIdx.x * BM * ldc + blockIdx.y * BN;

  const int wave = tid >> 6, lane = tid & 63;
  const int wm = (wave >> 1) * 64, wn = (wave & 1) * 64;
  const int lm = lane & 15, lq = lane >> 4;

  floatx4 acc[4][4] = {};

  const int sr = tid >> 3;          // staging row 0..31
  const int sc = (tid & 7) * 8;     // staging col chunk (elements)

  for (int kt = 0; kt < K; kt += BK) {
#pragma unroll
    for (int i = 0; i < 4; i++)
      async_cp16(A + (size_t)(sr + 32 * i) * lda + kt + sc,
                 (char*)As + i * 4096 + tid * 16);
#pragma unroll
    for (int i = 0; i < 4; i++)
      async_cp16(Bt + (size_t)(sr + 32 * i) * K + kt + sc,
                 (char*)Bs + i * 4096 + tid * 16);
    __syncthreads();   // drains vmcnt -> staged tiles visible
#pragma unroll
    for (int ks = 0; ks < 2; ks++) {
      short8 af[4], bf[4];
#pragma unroll
      for (int i = 0; i < 4; i++)
        af[i] = *(const short8*)(As + (wm + 16 * i + lm) * BK + ks * 32 + lq * 8);
#pragma unroll
      for (int j = 0; j < 4; j++)
        bf[j] = *(const short8*)(Bs + (wn + 16 * j + lm) * BK + ks * 32 + lq * 8);
#pragma unroll
      for (int i = 0; i < 4; i++)
#pragma unroll
        for (int j = 0; j < 4; j++)
          acc[i][j] = __builtin_amdgcn_mfma_f32_16x16x32_bf16(af[i], bf[j], acc[i][j], 0, 0, 0);
    }
    __syncthreads();   // protect LDS reuse next iter
  }

#pragma unroll
  for (int i = 0; i < 4; i++) {
    const int row = wm + 16 * i + lq * 4;
#pragma unroll
    for (int j = 0; j < 4; j++) {
      const int col = wn + 16 * j + lm;
      const float bv = bias[col];
#pragma unroll
      for (int v = 0; v < 4; v++) {
        float val = fmaxf(acc[i][j][v] + bv, 0.0f);
        C[(size_t)(row + v) * ldc + col] = f32_to_bf16(val);
      }
    }
  }
}

// ---------------- combine: tic[t,bl,h] = sum_e gates[t,b0+bl,e] * eoc[bl,e,h] ----------------
__global__ void combine_kernel(const unsigned short* __restrict__ eo,
                               const float* __restrict__ gates,
                               unsigned short* __restrict__ ti,
                               int b0, int Bc) {
  int tid = blockIdx.x * 256 + threadIdx.x;
  int bl = tid >> 6;                 // chunk-local row
  int hc = (tid & 63) << 3;
  float g[3][8];
#pragma unroll
  for (int t = 0; t < 3; t++) {
    const floatx4* gp = (const floatx4*)(gates + ((size_t)t * 16384 + b0 + bl) * 8);
    floatx4 g0 = gp[0], g1 = gp[1];
#pragma unroll
    for (int j = 0; j < 4; j++) { g[t][j] = g0[j]; g[t][4 + j] = g1[j]; }
  }
  float out[3][8] = {};
#pragma unroll
  for (int e = 0; e < 8; e++) {
    ushortx8 v = *(const ushortx8*)(eo + ((size_t)bl * 8 + e) * 512 + hc);
#pragma unroll
    for (int j = 0; j < 8; j++) {
      float f = bf16_to_f32(v[j]);
#pragma unroll
      for (int t = 0; t < 3; t++) out[t][j] += g[t][e] * f;
    }
  }
#pragma unroll
  for (int t = 0; t < 3; t++) {
    ushortx8 o;
#pragma unroll
    for (int j = 0; j < 8; j++) o[j] = f32_to_bf16(out[t][j]);
    *(ushortx8*)(ti + ((size_t)t * Bc + bl) * 512 + hc) = o;
  }
}

// ---------------- tower2: out[t*16384+b0+bl] = sigmoid(thc[t,bl,:] . Wt2[t] + bt2[t]) ----------------
__global__ void tower2_kernel(const unsigned short* __restrict__ th,
                              const float* __restrict__ Wt2,
                              const float* __restrict__ bt2,
                              float* __restrict__ out,
                              int b0, int bcShift) {
  int wave = threadIdx.x >> 6, lane = threadIdx.x & 63;
  int row = blockIdx.x * 4 + wave;       // 0 .. 3*Bc-1 ; row = t*Bc + bl
  int t = row >> bcShift;
  int bl = row & ((1 << bcShift) - 1);
  const unsigned short* r = th + (size_t)row * 256;
  int k = lane * 4;
  ushortx4 v = *(const ushortx4*)(r + k);
  float a = 0.f;
#pragma unroll
  for (int j = 0; j < 4; j++) a += bf16_to_f32(v[j]) * Wt2[t * 256 + k + j];
#pragma unroll
  for (int off = 32; off > 0; off >>= 1) a += __shfl_xor(a, off, 64);
  if (lane == 0) out[(t << 14) + b0 + bl] = 1.f / (1.f + __expf(-(a + bt2[t])));
}

extern "C" void kernel_launch(void* const* d_in, const int* in_sizes, int n_in,
                              void* d_out, int out_size, void* d_ws, size_t ws_size,
                              hipStream_t stream) {
  (void)in_sizes; (void)n_in; (void)out_size;
  const float* x   = (const float*)d_in[0];
  const float* We1 = (const float*)d_in[1];
  const float* be1 = (const float*)d_in[2];
  const float* We2 = (const float*)d_in[3];
  const float* be2 = (const float*)d_in[4];
  const float* Wg  = (const float*)d_in[5];
  const float* bg  = (const float*)d_in[6];
  const float* Wt1 = (const float*)d_in[7];
  const float* bt1 = (const float*)d_in[8];
  const float* Wt2 = (const float*)d_in[9];
  const float* bt2 = (const float*)d_in[10];
  float* out = (float*)d_out;

  char* ws = (char*)d_ws;
  unsigned short* xb   = (unsigned short*)(ws + 0);            // 33,554,432
  unsigned short* W1T  = (unsigned short*)(ws + 33554432);     //  8,388,608
  unsigned short* W2T  = (unsigned short*)(ws + 41943040);     //  4,194,304
  unsigned short* Wt1T = (unsigned short*)(ws + 46137344);     //    786,432
  float*          gts  = (float*)(ws + 46923776);              //  1,572,864
  float*          WgT  = (float*)(ws + 48496640);              //     98,304
  const size_t fixed = 48594944;

  // Adaptive chunk size: per-chunk buffers need Bc*20992 bytes.
  size_t rem = ws_size > fixed ? ws_size - fixed : 0;
  int Bc = 8192;
  while (Bc > 512 && (size_t)Bc * 20992 > rem) Bc >>= 1;
  const int nc = 16384 / Bc;
  int bcShift = 0;
  while ((1 << bcShift) < Bc) bcShift++;

  char* cb = ws + fixed;
  unsigned short* h1c = (unsigned short*)(cb);                                    // Bc*8192 B
  unsigned short* eoc = (unsigned short*)(cb + (size_t)Bc * 8192);                // Bc*8192 B
  unsigned short* tic = (unsigned short*)(cb + (size_t)Bc * 16384);               // Bc*3072 B
  unsigned short* thc = (unsigned short*)(cb + (size_t)Bc * 16384 + (size_t)Bc * 3072); // Bc*1536 B

  // --- prologue (chunk-independent) ---
  cvt_x_kernel<<<16384, 256, 0, stream>>>(x, xb);
  transpose_cvt_kernel<<<dim3(16, 32, 8), dim3(32, 8), 0, stream>>>(We1, W1T, 1024, 512);
  transpose_cvt_kernel<<<dim3(16, 16, 8), dim3(32, 8), 0, stream>>>(We2, W2T, 512, 512);
  transpose_cvt_kernel<<<dim3(8, 16, 3),  dim3(32, 8), 0, stream>>>(Wt1, Wt1T, 512, 256);
  transpose_wg_kernel<<<96, 256, 0, stream>>>(Wg, WgT);
  gates_kernel<<<4096, 256, 0, stream>>>(x, WgT, bg, gts);

  // --- per-chunk pipeline ---
  for (int c = 0; c < nc; c++) {
    const unsigned short* xbc = xb + (size_t)c * Bc * 1024;
    // h1c = relu(x_chunk @ We1 + be1)     M=Bc N=512 K=1024 per expert
    gemm_bt_relu<<<dim3(Bc / 128, 4, 8), 256, 0, stream>>>(
        xbc, 0L, 1024, W1T, 524288L, be1, 512, h1c, 512L, 4096, 1024);
    // eoc = relu(h1c @ We2 + be2)         M=Bc N=512 K=512 per expert
    gemm_bt_relu<<<dim3(Bc / 128, 4, 8), 256, 0, stream>>>(
        h1c, 512L, 4096, W2T, 262144L, be2, 512, eoc, 512L, 4096, 512);
    // tic[t,bl,:] = sum_e g * eoc
    combine_kernel<<<Bc / 4, 256, 0, stream>>>(eoc, gts, tic, c * Bc, Bc);
    // thc = relu(tic @ Wt1 + bt1)         M=Bc N=256 K=512 per task
    gemm_bt_relu<<<dim3(Bc / 128, 2, 3), 256, 0, stream>>>(
        tic, (long)Bc * 512, 512, Wt1T, 131072L, bt1, 256, thc, (long)Bc * 256, 256, 512);
    // out
    tower2_kernel<<<3 * Bc / 4, 256, 0, stream>>>(thc, Wt2, bt2, out, c * Bc, bcShift);
  }
}

// Round 4
// 521.438 us; speedup vs baseline: 1.3450x; 1.1382x over previous
//
#include <hip/hip_runtime.h>

// MMoE: B=16384, D=1024, E=8, H=512, T=256, TASKS=3
// Batch-chunked pipeline (chunk size Bc chosen at launch from ws_size).
//
// R2: 701 us (gates stride-8 reads, 167 us).
// R3: 593 us; GEMM1=123 us with SQ_LDS_BANK_CONFLICT=2.5e7 (~12 cyc/ds_read):
//     LDS row stride 128 B = 32 banks -> 16-way conflicts on fragment reads.
// R4: XOR-swizzle LDS chunks (slot (row,c') holds global chunk c'^(row&7)).
//     global_load_lds dest is forced contiguous, so the swizzle is applied on
//     the per-lane GLOBAL source column; read side XORs with lm&7. 2-way
//     aliasing remains (free per m136).

#define BM 128
#define BN 128
#define BK 64

typedef __attribute__((ext_vector_type(8))) short short8;
typedef __attribute__((ext_vector_type(4))) float floatx4;
typedef __attribute__((ext_vector_type(4))) unsigned short ushortx4;
typedef __attribute__((ext_vector_type(8))) unsigned short ushortx8;

__device__ __forceinline__ unsigned short f32_to_bf16(float f) {
  unsigned int u = __float_as_uint(f);
  u += 0x7fffu + ((u >> 16) & 1u);   // round-to-nearest-even (no NaNs in this net)
  return (unsigned short)(u >> 16);
}
__device__ __forceinline__ float bf16_to_f32(unsigned short h) {
  return __uint_as_float(((unsigned int)h) << 16);
}

__device__ __forceinline__ void async_cp16(const void* g, void* lds) {
  __builtin_amdgcn_global_load_lds(
      (const __attribute__((address_space(1))) void*)g,
      (__attribute__((address_space(3))) void*)lds, 16, 0, 0);
}

// ---------------- fp32 -> bf16 convert (x) ----------------
__global__ void cvt_x_kernel(const float* __restrict__ x, unsigned short* __restrict__ xb) {
  size_t i = ((size_t)blockIdx.x * blockDim.x + threadIdx.x) * 4;
  floatx4 v = *(const floatx4*)(x + i);
  ushortx4 o;
#pragma unroll
  for (int j = 0; j < 4; j++) o[j] = f32_to_bf16(v[j]);
  *(ushortx4*)(xb + i) = o;
}

// ---------------- [z][K][N] fp32 -> [z][N][K] bf16 ----------------
__global__ void transpose_cvt_kernel(const float* __restrict__ in,
                                     unsigned short* __restrict__ out,
                                     int K, int N) {
  __shared__ float tile[32][33];
  const size_t zoff = (size_t)blockIdx.z * K * N;
  int n0 = blockIdx.x * 32, k0 = blockIdx.y * 32;
  for (int i = threadIdx.y; i < 32; i += 8)
    tile[i][threadIdx.x] = in[zoff + (size_t)(k0 + i) * N + n0 + threadIdx.x];
  __syncthreads();
  for (int i = threadIdx.y; i < 32; i += 8)
    out[zoff + (size_t)(n0 + i) * K + k0 + threadIdx.x] = f32_to_bf16(tile[threadIdx.x][i]);
}

// ---------------- Wg [3][1024][8] fp32 -> WgT [3][8][1024] fp32 ----------------
__global__ void transpose_wg_kernel(const float* __restrict__ in, float* __restrict__ out) {
  int idx = blockIdx.x * 256 + threadIdx.x;   // 24576 total
  int t = idx >> 13, r = idx & 8191;
  int e = r >> 10, d = r & 1023;
  out[idx] = in[t * 8192 + d * 8 + e];
}

// ---------------- gates: coalesced fp32 logits + softmax over E=8 ----------------
// WgT: [3][8][1024] fp32. One wave per batch row.
__global__ __launch_bounds__(256) void gates_kernel(
    const float* __restrict__ x, const float* __restrict__ WgT,
    const float* __restrict__ bg, float* __restrict__ gout) {
  int wave = threadIdx.x >> 6, lane = threadIdx.x & 63;
  int b = blockIdx.x * 4 + wave;
  const float* xr = x + (size_t)b * 1024;
  float xv[16];
#pragma unroll
  for (int j = 0; j < 16; j++) xv[j] = xr[lane + 64 * j];
  float mylogit = 0.f;
#pragma unroll
  for (int te = 0; te < 24; te++) {
    const float* w = WgT + te * 1024;
    float a = 0.f;
#pragma unroll
    for (int j = 0; j < 16; j++) a += xv[j] * w[lane + 64 * j];
#pragma unroll
    for (int off = 32; off > 0; off >>= 1) a += __shfl_xor(a, off, 64);
    if (lane == te) mylogit = a;   // compile-time te -> cndmask, no LDS
  }
  if (lane < 24) {   // groups of 8 (tasks) are 8-lane aligned; xor 4/2/1 stays in-group
    int t = lane >> 3, e = lane & 7;
    float logit = mylogit + bg[lane];
    float m = logit;
    m = fmaxf(m, __shfl_xor(m, 4, 64));
    m = fmaxf(m, __shfl_xor(m, 2, 64));
    m = fmaxf(m, __shfl_xor(m, 1, 64));
    float ex = __expf(logit - m);
    float s = ex;
    s += __shfl_xor(s, 4, 64);
    s += __shfl_xor(s, 2, 64);
    s += __shfl_xor(s, 1, 64);
    gout[(size_t)t * 131072 + (size_t)b * 8 + e] = ex / s;
  }
}

// ---------------- m97-style bf16 GEMM: C = relu(A * B^T + bias), bf16 out ----------------
// LDS layout XOR-swizzled: slot (row, chunk c') holds global 16B-chunk
// c' ^ (row & 7). Staging permutes the per-lane global source column;
// fragment reads XOR the chunk index with (row & 7) = (lm & 7).
__global__ __launch_bounds__(256) void gemm_bt_relu(
    const unsigned short* __restrict__ Abase, long aOffZ, int lda,
    const unsigned short* __restrict__ Bbase, long bOffZ,
    const float* __restrict__ biasBase, int biasOffZ,
    unsigned short* __restrict__ Cbase, long cOffZ, int ldc,
    int K) {
  __shared__ __align__(16) unsigned short As[BM * BK];
  __shared__ __align__(16) unsigned short Bs[BN * BK];
  const int tid = threadIdx.x;
  const int z = blockIdx.z;
  const unsigned short* A = Abase + (size_t)aOffZ * z + (size_t)blockIdx.x * BM * lda;
  const unsigned short* Bt = Bbase + (size_t)bOffZ * z + (size_t)blockIdx.y * BN * K;
  const float* bias = biasBase + (size_t)biasOffZ * z + blockIdx.y * BN;
  unsigned short* C = Cbase + (size_t)cOffZ * z + (size_t)blockIdx.x * BM * ldc + blockIdx.y * BN;

  const int wave = tid >> 6, lane = tid & 63;
  const int wm = (wave >> 1) * 64, wn = (wave & 1) * 64;
  const int lm = lane & 15, lq = lane >> 4;
  const int sw = lm & 7;            // read-side swizzle key (= row & 7)

  floatx4 acc[4][4] = {};

  const int sr = tid >> 3;                               // staging row 0..31
  const int sc = (((tid & 7) ^ (sr & 7)) << 3);          // swizzled source col (elements)

  for (int kt = 0; kt < K; kt += BK) {
#pragma unroll
    for (int i = 0; i < 4; i++)
      async_cp16(A + (size_t)(sr + 32 * i) * lda + kt + sc,
                 (char*)As + i * 4096 + tid * 16);
#pragma unroll
    for (int i = 0; i < 4; i++)
      async_cp16(Bt + (size_t)(sr + 32 * i) * K + kt + sc,
                 (char*)Bs + i * 4096 + tid * 16);
    __syncthreads();   // drains vmcnt -> staged tiles visible
#pragma unroll
    for (int ks = 0; ks < 2; ks++) {
      short8 af[4], bf[4];
      const int ch = ((ks * 4 + lq) ^ sw) << 3;          // swizzled chunk (elements)
#pragma unroll
      for (int i = 0; i < 4; i++)
        af[i] = *(const short8*)(As + (wm + 16 * i + lm) * BK + ch);
#pragma unroll
      for (int j = 0; j < 4; j++)
        bf[j] = *(const short8*)(Bs + (wn + 16 * j + lm) * BK + ch);
#pragma unroll
      for (int i = 0; i < 4; i++)
#pragma unroll
        for (int j = 0; j < 4; j++)
          acc[i][j] = __builtin_amdgcn_mfma_f32_16x16x32_bf16(af[i], bf[j], acc[i][j], 0, 0, 0);
    }
    __syncthreads();   // protect LDS reuse next iter
  }

#pragma unroll
  for (int i = 0; i < 4; i++) {
    const int row = wm + 16 * i + lq * 4;
#pragma unroll
    for (int j = 0; j < 4; j++) {
      const int col = wn + 16 * j + lm;
      const float bv = bias[col];
#pragma unroll
      for (int v = 0; v < 4; v++) {
        float val = fmaxf(acc[i][j][v] + bv, 0.0f);
        C[(size_t)(row + v) * ldc + col] = f32_to_bf16(val);
      }
    }
  }
}

// ---------------- combine: tic[t,bl,h] = sum_e gates[t,b0+bl,e] * eoc[bl,e,h] ----------------
__global__ void combine_kernel(const unsigned short* __restrict__ eo,
                               const float* __restrict__ gates,
                               unsigned short* __restrict__ ti,
                               int b0, int Bc) {
  int tid = blockIdx.x * 256 + threadIdx.x;
  int bl = tid >> 6;                 // chunk-local row
  int hc = (tid & 63) << 3;
  float g[3][8];
#pragma unroll
  for (int t = 0; t < 3; t++) {
    const floatx4* gp = (const floatx4*)(gates + ((size_t)t * 16384 + b0 + bl) * 8);
    floatx4 g0 = gp[0], g1 = gp[1];
#pragma unroll
    for (int j = 0; j < 4; j++) { g[t][j] = g0[j]; g[t][4 + j] = g1[j]; }
  }
  float out[3][8] = {};
#pragma unroll
  for (int e = 0; e < 8; e++) {
    ushortx8 v = *(const ushortx8*)(eo + ((size_t)bl * 8 + e) * 512 + hc);
#pragma unroll
    for (int j = 0; j < 8; j++) {
      float f = bf16_to_f32(v[j]);
#pragma unroll
      for (int t = 0; t < 3; t++) out[t][j] += g[t][e] * f;
    }
  }
#pragma unroll
  for (int t = 0; t < 3; t++) {
    ushortx8 o;
#pragma unroll
    for (int j = 0; j < 8; j++) o[j] = f32_to_bf16(out[t][j]);
    *(ushortx8*)(ti + ((size_t)t * Bc + bl) * 512 + hc) = o;
  }
}

// ---------------- tower2: out[t*16384+b0+bl] = sigmoid(thc[t,bl,:] . Wt2[t] + bt2[t]) ----------------
__global__ void tower2_kernel(const unsigned short* __restrict__ th,
                              const float* __restrict__ Wt2,
                              const float* __restrict__ bt2,
                              float* __restrict__ out,
                              int b0, int bcShift) {
  int wave = threadIdx.x >> 6, lane = threadIdx.x & 63;
  int row = blockIdx.x * 4 + wave;       // 0 .. 3*Bc-1 ; row = t*Bc + bl
  int t = row >> bcShift;
  int bl = row & ((1 << bcShift) - 1);
  const unsigned short* r = th + (size_t)row * 256;
  int k = lane * 4;
  ushortx4 v = *(const ushortx4*)(r + k);
  float a = 0.f;
#pragma unroll
  for (int j = 0; j < 4; j++) a += bf16_to_f32(v[j]) * Wt2[t * 256 + k + j];
#pragma unroll
  for (int off = 32; off > 0; off >>= 1) a += __shfl_xor(a, off, 64);
  if (lane == 0) out[(t << 14) + b0 + bl] = 1.f / (1.f + __expf(-(a + bt2[t])));
}

extern "C" void kernel_launch(void* const* d_in, const int* in_sizes, int n_in,
                              void* d_out, int out_size, void* d_ws, size_t ws_size,
                              hipStream_t stream) {
  (void)in_sizes; (void)n_in; (void)out_size;
  const float* x   = (const float*)d_in[0];
  const float* We1 = (const float*)d_in[1];
  const float* be1 = (const float*)d_in[2];
  const float* We2 = (const float*)d_in[3];
  const float* be2 = (const float*)d_in[4];
  const float* Wg  = (const float*)d_in[5];
  const float* bg  = (const float*)d_in[6];
  const float* Wt1 = (const float*)d_in[7];
  const float* bt1 = (const float*)d_in[8];
  const float* Wt2 = (const float*)d_in[9];
  const float* bt2 = (const float*)d_in[10];
  float* out = (float*)d_out;

  char* ws = (char*)d_ws;
  unsigned short* xb   = (unsigned short*)(ws + 0);            // 33,554,432
  unsigned short* W1T  = (unsigned short*)(ws + 33554432);     //  8,388,608
  unsigned short* W2T  = (unsigned short*)(ws + 41943040);     //  4,194,304
  unsigned short* Wt1T = (unsigned short*)(ws + 46137344);     //    786,432
  float*          gts  = (float*)(ws + 46923776);              //  1,572,864
  float*          WgT  = (float*)(ws + 48496640);              //     98,304
  const size_t fixed = 48594944;

  // Adaptive chunk size: per-chunk buffers need Bc*20992 bytes.
  size_t rem = ws_size > fixed ? ws_size - fixed : 0;
  int Bc = 8192;
  while (Bc > 512 && (size_t)Bc * 20992 > rem) Bc >>= 1;
  const int nc = 16384 / Bc;
  int bcShift = 0;
  while ((1 << bcShift) < Bc) bcShift++;

  char* cb = ws + fixed;
  unsigned short* h1c = (unsigned short*)(cb);                                    // Bc*8192 B
  unsigned short* eoc = (unsigned short*)(cb + (size_t)Bc * 8192);                // Bc*8192 B
  unsigned short* tic = (unsigned short*)(cb + (size_t)Bc * 16384);               // Bc*3072 B
  unsigned short* thc = (unsigned short*)(cb + (size_t)Bc * 16384 + (size_t)Bc * 3072); // Bc*1536 B

  // --- prologue (chunk-independent) ---
  cvt_x_kernel<<<16384, 256, 0, stream>>>(x, xb);
  transpose_cvt_kernel<<<dim3(16, 32, 8), dim3(32, 8), 0, stream>>>(We1, W1T, 1024, 512);
  transpose_cvt_kernel<<<dim3(16, 16, 8), dim3(32, 8), 0, stream>>>(We2, W2T, 512, 512);
  transpose_cvt_kernel<<<dim3(8, 16, 3),  dim3(32, 8), 0, stream>>>(Wt1, Wt1T, 512, 256);
  transpose_wg_kernel<<<96, 256, 0, stream>>>(Wg, WgT);
  gates_kernel<<<4096, 256, 0, stream>>>(x, WgT, bg, gts);

  // --- per-chunk pipeline ---
  for (int c = 0; c < nc; c++) {
    const unsigned short* xbc = xb + (size_t)c * Bc * 1024;
    // h1c = relu(x_chunk @ We1 + be1)     M=Bc N=512 K=1024 per expert
    gemm_bt_relu<<<dim3(Bc / 128, 4, 8), 256, 0, stream>>>(
        xbc, 0L, 1024, W1T, 524288L, be1, 512, h1c, 512L, 4096, 1024);
    // eoc = relu(h1c @ We2 + be2)         M=Bc N=512 K=512 per expert
    gemm_bt_relu<<<dim3(Bc / 128, 4, 8), 256, 0, stream>>>(
        h1c, 512L, 4096, W2T, 262144L, be2, 512, eoc, 512L, 4096, 512);
    // tic[t,bl,:] = sum_e g * eoc
    combine_kernel<<<Bc / 4, 256, 0, stream>>>(eoc, gts, tic, c * Bc, Bc);
    // thc = relu(tic @ Wt1 + bt1)         M=Bc N=256 K=512 per task
    gemm_bt_relu<<<dim3(Bc / 128, 2, 3), 256, 0, stream>>>(
        tic, (long)Bc * 512, 512, Wt1T, 131072L, bt1, 256, thc, (long)Bc * 256, 256, 512);
    // out
    tower2_kernel<<<3 * Bc / 4, 256, 0, stream>>>(thc, Wt2, bt2, out, c * Bc, bcShift);
  }
}

// Round 5
// 498.077 us; speedup vs baseline: 1.4081x; 1.0469x over previous
//
#include <hip/hip_runtime.h>

// MMoE: B=16384, D=1024, E=8, H=512, T=256, TASKS=3
// R2: 701 us (gates stride-8 reads). R3: 593 us (coalesced gates).
// R4: 521 us (XOR-swizzled GEMM LDS -> bank conflicts 2.5e7 -> 0,
//     GEMM1 123 -> 84 us = ~818 TF, at the m97-structure plateau).
// R5: fuse the tail: cvt_x->gates, tower1+tower2 single kernel (in-register
//     Wt2 dot from MFMA accs), all weight transposes in one prep kernel,
//     Bc cap 16384. 16 -> 10 launches.
//
// Workspace: fixed 48,594,944 B + Bc*19456 B chunk buffers (Bc adapts).

#define BM 128
#define BN 128
#define BK 64

typedef __attribute__((ext_vector_type(8))) short short8;
typedef __attribute__((ext_vector_type(4))) float floatx4;
typedef __attribute__((ext_vector_type(4))) unsigned short ushortx4;
typedef __attribute__((ext_vector_type(8))) unsigned short ushortx8;

__device__ __forceinline__ unsigned short f32_to_bf16(float f) {
  unsigned int u = __float_as_uint(f);
  u += 0x7fffu + ((u >> 16) & 1u);   // round-to-nearest-even (no NaNs in this net)
  return (unsigned short)(u >> 16);
}
__device__ __forceinline__ float bf16_to_f32(unsigned short h) {
  return __uint_as_float(((unsigned int)h) << 16);
}

__device__ __forceinline__ void async_cp16(const void* g, void* lds) {
  __builtin_amdgcn_global_load_lds(
      (const __attribute__((address_space(1))) void*)g,
      (__attribute__((address_space(3))) void*)lds, 16, 0, 0);
}

// ---------------- all weight prep in one kernel ----------------
// grid (16,32,20), block (32,8):
//   z 0..7  : We1 slice z  [1024][512] -> W1T  [512][1024] bf16
//   z 8..15 : We2 slice    [512][512]  -> W2T  [512][512]  bf16 (y<16)
//   z 16..18: Wt1 slice    [512][256]  -> Wt1T [256][512]  bf16 (x<8,y<16)
//   z 19    : Wg [3][1024][8] -> WgT [3][8][1024] fp32      (x<16,y<6)
__device__ __forceinline__ void transpose_slice(
    const float* __restrict__ in, unsigned short* __restrict__ out,
    int K, int N, float (*tile)[33]) {
  int n0 = blockIdx.x * 32, k0 = blockIdx.y * 32;
  for (int i = threadIdx.y; i < 32; i += 8)
    tile[i][threadIdx.x] = in[(size_t)(k0 + i) * N + n0 + threadIdx.x];
  __syncthreads();
  for (int i = threadIdx.y; i < 32; i += 8)
    out[(size_t)(n0 + i) * K + k0 + threadIdx.x] = f32_to_bf16(tile[threadIdx.x][i]);
}

__global__ void prep_kernel(const float* __restrict__ We1, const float* __restrict__ We2,
                            const float* __restrict__ Wt1, const float* __restrict__ Wg,
                            unsigned short* __restrict__ W1T, unsigned short* __restrict__ W2T,
                            unsigned short* __restrict__ Wt1T, float* __restrict__ WgT) {
  __shared__ float tile[32][33];
  int z = blockIdx.z;
  if (z < 8) {
    transpose_slice(We1 + (size_t)z * 524288, W1T + (size_t)z * 524288, 1024, 512, tile);
  } else if (z < 16) {
    if (blockIdx.y < 16)
      transpose_slice(We2 + (size_t)(z - 8) * 262144, W2T + (size_t)(z - 8) * 262144, 512, 512, tile);
  } else if (z < 19) {
    if (blockIdx.x < 8 && blockIdx.y < 16)
      transpose_slice(Wt1 + (size_t)(z - 16) * 131072, Wt1T + (size_t)(z - 16) * 131072, 512, 256, tile);
  } else {
    if (blockIdx.x < 16 && blockIdx.y < 6) {
      int idx = (blockIdx.y * 16 + blockIdx.x) * 256 + threadIdx.y * 32 + threadIdx.x;
      int t = idx >> 13, r = idx & 8191, e = r >> 10, d = r & 1023;
      WgT[idx] = Wg[t * 8192 + d * 8 + e];
    }
  }
}

// ---------------- gates + x->bf16 (fused; reads x once) ----------------
// WgT: [3][8][1024] fp32. One wave per batch row.
__global__ __launch_bounds__(256) void gates_cvt_kernel(
    const float* __restrict__ x, const float* __restrict__ WgT,
    const float* __restrict__ bg, float* __restrict__ gout,
    unsigned short* __restrict__ xb) {
  int wave = threadIdx.x >> 6, lane = threadIdx.x & 63;
  int b = blockIdx.x * 4 + wave;
  const float* xr = x + (size_t)b * 1024;
  float xv[16];
#pragma unroll
  for (int j = 0; j < 16; j++) xv[j] = xr[lane + 64 * j];
  unsigned short* xbr = xb + (size_t)b * 1024;
#pragma unroll
  for (int j = 0; j < 16; j++) xbr[lane + 64 * j] = f32_to_bf16(xv[j]);
  float mylogit = 0.f;
#pragma unroll
  for (int te = 0; te < 24; te++) {
    const float* w = WgT + te * 1024;
    float a = 0.f;
#pragma unroll
    for (int j = 0; j < 16; j++) a += xv[j] * w[lane + 64 * j];
#pragma unroll
    for (int off = 32; off > 0; off >>= 1) a += __shfl_xor(a, off, 64);
    if (lane == te) mylogit = a;   // compile-time te -> cndmask, no LDS
  }
  if (lane < 24) {   // groups of 8 (tasks) are 8-lane aligned; xor 4/2/1 stays in-group
    int t = lane >> 3, e = lane & 7;
    float logit = mylogit + bg[lane];
    float m = logit;
    m = fmaxf(m, __shfl_xor(m, 4, 64));
    m = fmaxf(m, __shfl_xor(m, 2, 64));
    m = fmaxf(m, __shfl_xor(m, 1, 64));
    float ex = __expf(logit - m);
    float s = ex;
    s += __shfl_xor(s, 4, 64);
    s += __shfl_xor(s, 2, 64);
    s += __shfl_xor(s, 1, 64);
    gout[(size_t)t * 131072 + (size_t)b * 8 + e] = ex / s;
  }
}

// ---------------- m97-style bf16 GEMM: C = relu(A * B^T + bias), bf16 out ----------------
// LDS XOR-swizzled: slot (row, chunk c') holds global 16B-chunk c'^(row&7).
__global__ __launch_bounds__(256) void gemm_bt_relu(
    const unsigned short* __restrict__ Abase, long aOffZ, int lda,
    const unsigned short* __restrict__ Bbase, long bOffZ,
    const float* __restrict__ biasBase, int biasOffZ,
    unsigned short* __restrict__ Cbase, long cOffZ, int ldc,
    int K) {
  __shared__ __align__(16) unsigned short As[BM * BK];
  __shared__ __align__(16) unsigned short Bs[BN * BK];
  const int tid = threadIdx.x;
  const int z = blockIdx.z;
  const unsigned short* A = Abase + (size_t)aOffZ * z + (size_t)blockIdx.x * BM * lda;
  const unsigned short* Bt = Bbase + (size_t)bOffZ * z + (size_t)blockIdx.y * BN * K;
  const float* bias = biasBase + (size_t)biasOffZ * z + blockIdx.y * BN;
  unsigned short* C = Cbase + (size_t)cOffZ * z + (size_t)blockIdx.x * BM * ldc + blockIdx.y * BN;

  const int wave = tid >> 6, lane = tid & 63;
  const int wm = (wave >> 1) * 64, wn = (wave & 1) * 64;
  const int lm = lane & 15, lq = lane >> 4;
  const int sw = lm & 7;            // read-side swizzle key (= row & 7)

  floatx4 acc[4][4] = {};

  const int sr = tid >> 3;                               // staging row 0..31
  const int sc = (((tid & 7) ^ (sr & 7)) << 3);          // swizzled source col (elements)

  for (int kt = 0; kt < K; kt += BK) {
#pragma unroll
    for (int i = 0; i < 4; i++)
      async_cp16(A + (size_t)(sr + 32 * i) * lda + kt + sc,
                 (char*)As + i * 4096 + tid * 16);
#pragma unroll
    for (int i = 0; i < 4; i++)
      async_cp16(Bt + (size_t)(sr + 32 * i) * K + kt + sc,
                 (char*)Bs + i * 4096 + tid * 16);
    __syncthreads();   // drains vmcnt -> staged tiles visible
#pragma unroll
    for (int ks = 0; ks < 2; ks++) {
      short8 af[4], bf[4];
      const int ch = ((ks * 4 + lq) ^ sw) << 3;          // swizzled chunk (elements)
#pragma unroll
      for (int i = 0; i < 4; i++)
        af[i] = *(const short8*)(As + (wm + 16 * i + lm) * BK + ch);
#pragma unroll
      for (int j = 0; j < 4; j++)
        bf[j] = *(const short8*)(Bs + (wn + 16 * j + lm) * BK + ch);
#pragma unroll
      for (int i = 0; i < 4; i++)
#pragma unroll
        for (int j = 0; j < 4; j++)
          acc[i][j] = __builtin_amdgcn_mfma_f32_16x16x32_bf16(af[i], bf[j], acc[i][j], 0, 0, 0);
    }
    __syncthreads();   // protect LDS reuse next iter
  }

#pragma unroll
  for (int i = 0; i < 4; i++) {
    const int row = wm + 16 * i + lq * 4;
#pragma unroll
    for (int j = 0; j < 4; j++) {
      const int col = wn + 16 * j + lm;
      const float bv = bias[col];
#pragma unroll
      for (int v = 0; v < 4; v++) {
        float val = fmaxf(acc[i][j][v] + bv, 0.0f);
        C[(size_t)(row + v) * ldc + col] = f32_to_bf16(val);
      }
    }
  }
}

// ---------------- combine: tic[t,bl,h] = sum_e gates[t,b0+bl,e] * eoc[bl,e,h] ----------------
__global__ void combine_kernel(const unsigned short* __restrict__ eo,
                               const float* __restrict__ gates,
                               unsigned short* __restrict__ ti,
                               int b0, int Bc) {
  int tid = blockIdx.x * 256 + threadIdx.x;
  int bl = tid >> 6;                 // chunk-local row
  int hc = (tid & 63) << 3;
  float g[3][8];
#pragma unroll
  for (int t = 0; t < 3; t++) {
    const floatx4* gp = (const floatx4*)(gates + ((size_t)t * 16384 + b0 + bl) * 8);
    floatx4 g0 = gp[0], g1 = gp[1];
#pragma unroll
    for (int j = 0; j < 4; j++) { g[t][j] = g0[j]; g[t][4 + j] = g1[j]; }
  }
  float out[3][8] = {};
#pragma unroll
  for (int e = 0; e < 8; e++) {
    ushortx8 v = *(const ushortx8*)(eo + ((size_t)bl * 8 + e) * 512 + hc);
#pragma unroll
    for (int j = 0; j < 8; j++) {
      float f = bf16_to_f32(v[j]);
#pragma unroll
      for (int t = 0; t < 3; t++) out[t][j] += g[t][e] * f;
    }
  }
#pragma unroll
  for (int t = 0; t < 3; t++) {
    ushortx8 o;
#pragma unroll
    for (int j = 0; j < 8; j++) o[j] = f32_to_bf16(out[t][j]);
    *(ushortx8*)(ti + ((size_t)t * Bc + bl) * 512 + hc) = o;
  }
}

// ---------------- fused towers: preds = sigmoid(relu(tic @ Wt1 + bt1) . Wt2 + bt2) ----------------
// 512 threads (8 waves), tile 128x256 (full tower width), K=512.
// Wave grid 2x4: wm=(w>>2)*64, wn=(w&3)*64. Same XOR-swizzled LDS as gemm_bt_relu.
// Epilogue: per-lane partial dot over its 4 cols/j, 16-lane shfl tree, 2KB LDS
// cross-wave (4 wn-groups) reduce, sigmoid, write 128 fp32 outputs.
__global__ __launch_bounds__(512) void tower_fused_kernel(
    const unsigned short* __restrict__ tic, const unsigned short* __restrict__ Wt1T,
    const float* __restrict__ bt1, const float* __restrict__ Wt2,
    const float* __restrict__ bt2, float* __restrict__ out,
    int b0, int Bc) {
  __shared__ __align__(16) unsigned short As[128 * 64];   // 16 KB (reused for partials)
  __shared__ __align__(16) unsigned short Bs[256 * 64];   // 32 KB
  const int tid = threadIdx.x;
  const int mtiles = Bc >> 7;
  const int t = blockIdx.x / mtiles;            // task
  const int xbl = blockIdx.x % mtiles;          // m-tile within task
  const unsigned short* A = tic + ((size_t)t * Bc + (size_t)xbl * 128) * 512;
  const unsigned short* Bt = Wt1T + (size_t)t * 131072;

  const int wave = tid >> 6, lane = tid & 63;
  const int wm = (wave >> 2) * 64, wn = (wave & 3) * 64;
  const int lm = lane & 15, lq = lane >> 4;
  const int sw = lm & 7;

  floatx4 acc[4][4] = {};

  const int sr = tid >> 3;                               // staging row 0..63
  const int sc = (((tid & 7) ^ (sr & 7)) << 3);

  for (int kt = 0; kt < 512; kt += 64) {
#pragma unroll
    for (int i = 0; i < 2; i++)
      async_cp16(A + (size_t)(sr + 64 * i) * 512 + kt + sc,
                 (char*)As + i * 8192 + tid * 16);
#pragma unroll
    for (int i = 0; i < 4; i++)
      async_cp16(Bt + (size_t)(sr + 64 * i) * 512 + kt + sc,
                 (char*)Bs + i * 8192 + tid * 16);
    __syncthreads();
#pragma unroll
    for (int ks = 0; ks < 2; ks++) {
      short8 af[4], bf[4];
      const int ch = ((ks * 4 + lq) ^ sw) << 3;
#pragma unroll
      for (int i = 0; i < 4; i++)
        af[i] = *(const short8*)(As + (wm + 16 * i + lm) * 64 + ch);
#pragma unroll
      for (int j = 0; j < 4; j++)
        bf[j] = *(const short8*)(Bs + (wn + 16 * j + lm) * 64 + ch);
#pragma unroll
      for (int i = 0; i < 4; i++)
#pragma unroll
        for (int j = 0; j < 4; j++)
          acc[i][j] = __builtin_amdgcn_mfma_f32_16x16x32_bf16(af[i], bf[j], acc[i][j], 0, 0, 0);
    }
    __syncthreads();
  }

  // Epilogue: th = relu(acc + bt1[col]); partial[row] += th * Wt2[col]
  float b1v[4], w2v[4];
#pragma unroll
  for (int j = 0; j < 4; j++) {
    int col = wn + 16 * j + lm;
    b1v[j] = bt1[t * 256 + col];
    w2v[j] = Wt2[t * 256 + col];
  }
  float* pt = (float*)As;   // 128 rows x 4 wn-groups
#pragma unroll
  for (int i = 0; i < 4; i++) {
#pragma unroll
    for (int v = 0; v < 4; v++) {
      float p = 0.f;
#pragma unroll
      for (int j = 0; j < 4; j++)
        p += fmaxf(acc[i][j][v] + b1v[j], 0.0f) * w2v[j];
      p += __shfl_xor(p, 1, 64);
      p += __shfl_xor(p, 2, 64);
      p += __shfl_xor(p, 4, 64);
      p += __shfl_xor(p, 8, 64);
      if (lm == 0) pt[(wm + 16 * i + lq * 4 + v) * 4 + (wave & 3)] = p;
    }
  }
  __syncthreads();
  if (tid < 128) {
    float s = pt[tid * 4] + pt[tid * 4 + 1] + pt[tid * 4 + 2] + pt[tid * 4 + 3] + bt2[t];
    out[(t << 14) + b0 + xbl * 128 + tid] = 1.f / (1.f + __expf(-s));
  }
}

extern "C" void kernel_launch(void* const* d_in, const int* in_sizes, int n_in,
                              void* d_out, int out_size, void* d_ws, size_t ws_size,
                              hipStream_t stream) {
  (void)in_sizes; (void)n_in; (void)out_size;
  const float* x   = (const float*)d_in[0];
  const float* We1 = (const float*)d_in[1];
  const float* be1 = (const float*)d_in[2];
  const float* We2 = (const float*)d_in[3];
  const float* be2 = (const float*)d_in[4];
  const float* Wg  = (const float*)d_in[5];
  const float* bg  = (const float*)d_in[6];
  const float* Wt1 = (const float*)d_in[7];
  const float* bt1 = (const float*)d_in[8];
  const float* Wt2 = (const float*)d_in[9];
  const float* bt2 = (const float*)d_in[10];
  float* out = (float*)d_out;

  char* ws = (char*)d_ws;
  unsigned short* xb   = (unsigned short*)(ws + 0);            // 33,554,432
  unsigned short* W1T  = (unsigned short*)(ws + 33554432);     //  8,388,608
  unsigned short* W2T  = (unsigned short*)(ws + 41943040);     //  4,194,304
  unsigned short* Wt1T = (unsigned short*)(ws + 46137344);     //    786,432
  float*          gts  = (float*)(ws + 46923776);              //  1,572,864
  float*          WgT  = (float*)(ws + 48496640);              //     98,304
  const size_t fixed = 48594944;

  // Adaptive chunk size: per-chunk buffers need Bc*19456 bytes (h1c+eoc+tic).
  size_t rem = ws_size > fixed ? ws_size - fixed : 0;
  int Bc = 16384;
  while (Bc > 512 && (size_t)Bc * 19456 > rem) Bc >>= 1;
  const int nc = 16384 / Bc;

  char* cb = ws + fixed;
  unsigned short* h1c = (unsigned short*)(cb);                      // Bc*8192 B
  unsigned short* eoc = (unsigned short*)(cb + (size_t)Bc * 8192);  // Bc*8192 B
  unsigned short* tic = (unsigned short*)(cb + (size_t)Bc * 16384); // Bc*3072 B

  // --- prologue ---
  prep_kernel<<<dim3(16, 32, 20), dim3(32, 8), 0, stream>>>(We1, We2, Wt1, Wg, W1T, W2T, Wt1T, WgT);
  gates_cvt_kernel<<<4096, 256, 0, stream>>>(x, WgT, bg, gts, xb);

  // --- per-chunk pipeline ---
  for (int c = 0; c < nc; c++) {
    const unsigned short* xbc = xb + (size_t)c * Bc * 1024;
    // h1c = relu(x_chunk @ We1 + be1)     M=Bc N=512 K=1024 per expert
    gemm_bt_relu<<<dim3(Bc / 128, 4, 8), 256, 0, stream>>>(
        xbc, 0L, 1024, W1T, 524288L, be1, 512, h1c, 512L, 4096, 1024);
    // eoc = relu(h1c @ We2 + be2)         M=Bc N=512 K=512 per expert
    gemm_bt_relu<<<dim3(Bc / 128, 4, 8), 256, 0, stream>>>(
        h1c, 512L, 4096, W2T, 262144L, be2, 512, eoc, 512L, 4096, 512);
    // tic[t,bl,:] = sum_e g * eoc
    combine_kernel<<<Bc / 4, 256, 0, stream>>>(eoc, gts, tic, c * Bc, Bc);
    // preds = sigmoid(relu(tic @ Wt1 + bt1) . Wt2 + bt2)
    tower_fused_kernel<<<3 * (Bc / 128), 512, 0, stream>>>(
        tic, Wt1T, bt1, Wt2, bt2, out, c * Bc, Bc);
  }
}